// Round 14
// baseline (222.693 us; speedup 1.0000x reference)
//
#include <hip/hip_runtime.h>
#include <hip/hip_bf16.h>
#include <stdint.h>
#include <stddef.h>

typedef __attribute__((ext_vector_type(8))) short short8;
typedef __attribute__((ext_vector_type(4))) float f32x4;
typedef __attribute__((ext_vector_type(4))) unsigned int u32x4;

#define DIM   512
#define NJ    17
#define NPART 5
#define NB    8192
#define KDIM  1536                  // 3 * 512
#define QROWS (NB*NPART)            // 40960
#define ROWB  (KDIM*2)              // 3072 bytes per Q row (bf16)

struct Cheb { float c[3][5][5]; };

__device__ __forceinline__ void gload_lds16(const void* g, void* l) {
  __builtin_amdgcn_global_load_lds((__attribute__((address_space(1))) void*)(g),
                                   (__attribute__((address_space(3))) void*)(l),
                                   16, 0, 0);
}

// ---------------- kernel A: pool + cheb -> Q bf16 (pre-swizzled) ----------------
// Unchanged champion pool (~70us, near BW roofline). Q row r = b*5+n; within
// each 128B K-block the 16B chunk index is XORed with (r&7) so a LINEAR
// global_load_lds yields the bank-conflict-free LDS layout in the GEMM.
__global__ __launch_bounds__(256) void pool_cheb_kernel(
    const float* __restrict__ x, __hip_bfloat16* __restrict__ Q, Cheb cb) {
  int gid = blockIdx.x * 256 + threadIdx.x;       // NB*128 threads
  int b  = gid >> 7;
  int c4 = gid & 127;                             // 4-elem d-chunk, d0 = c4*4
  const float* xb = x + (size_t)b * (NJ * DIM) + (c4 << 2);

  f32x4 pf[5];
#pragma unroll
  for (int p = 0; p < 5; ++p) pf[p] = (f32x4){0.f, 0.f, 0.f, 0.f};

  constexpr int jpart[NJ] = {2,0,0,0,1,1,1,2,2,2,2,3,3,3,4,4,4};
#pragma unroll
  for (int j = 0; j < NJ; ++j) {
    f32x4 a = __builtin_nontemporal_load(
        reinterpret_cast<const f32x4*>(xb + j * DIM));
    pf[jpart[j]] += a;
  }
  constexpr float scl[5] = {1.f/3.f, 1.f/3.f, 0.2f, 1.f/3.f, 1.f/3.f};
#pragma unroll
  for (int p = 0; p < 5; ++p) pf[p] *= scl[p];

  char* qb = reinterpret_cast<char*>(Q);
  int cj = c4 >> 1;                               // 16B chunk idx in k-segment
#pragma unroll
  for (int k = 0; k < 3; ++k) {
#pragma unroll
    for (int n = 0; n < 5; ++n) {
      int row = b * 5 + n;
      f32x4 s = cb.c[k][n][0] * pf[0] + cb.c[k][n][1] * pf[1] +
                cb.c[k][n][2] * pf[2] + cb.c[k][n][3] * pf[3] +
                cb.c[k][n][4] * pf[4];
      alignas(8) __hip_bfloat16 o[4];
#pragma unroll
      for (int i = 0; i < 4; ++i) o[i] = __float2bfloat16(s[i]);
      int swc = (cj & 7) ^ (row & 7);             // swizzled 16B chunk
      size_t off = (size_t)row * ROWB + (size_t)(k * 8 + (cj >> 3)) * 128 +
                   (size_t)swc * 16 + (size_t)(c4 & 1) * 8;
      *reinterpret_cast<ushort4*>(qb + off) = *reinterpret_cast<const ushort4*>(o);
    }
  }
}

// ---------------- kernel A2: w [3,512,512] f32 -> Wt3 k-chunk-major bf16 --------
// Wt3 layout: 16B fragment at ((ks*8 + kc)*512 + e)*16B holds 8 consecutive
// K-elems (k_cheb = ks>>3, d = (ks&7)*64 + kc*8 + i) of output-col e.
// MFMA B-fragments load from here COALESCED (lanes 0..15 = 256B contiguous),
// straight to registers -- B never goes through LDS.
__global__ __launch_bounds__(256) void wt3_kernel(
    const float* __restrict__ w, __hip_bfloat16* __restrict__ Wt3) {
  int c = blockIdx.x * 256 + threadIdx.x;     // 0..98303 fragment index
  int e   = c & 511;
  int kse = c >> 9;                           // 0..191
  int ks  = kse >> 3;
  int kc  = kse & 7;
  int k   = ks >> 3;
  int d0  = (ks & 7) * 64 + kc * 8;
  alignas(16) __hip_bfloat16 o[8];
#pragma unroll
  for (int i = 0; i < 8; ++i)
    o[i] = __float2bfloat16(w[(size_t)k * (DIM * DIM) + (size_t)(d0 + i) * DIM + e]);
  *reinterpret_cast<u32x4*>(reinterpret_cast<char*>(Wt3) + (size_t)c * 16) =
      *reinterpret_cast<const u32x4*>(o);
}

// ---------------- kernel B: 80x512 tile, B-direct-from-L2, 2 blocks/CU ----------
// Q (A-panels) read EXACTLY ONCE chip-wide (full-N tile). A-only LDS dbuf
// (2x10KB); B fragments loaded per-wave from L2-resident Wt3 into registers.
// 512 blocks at 2 blocks/CU: one block's epilogue write burst overlaps the
// co-resident block's K-loop (the overlap r13 failed to get at 1 block/CU).
__global__ __launch_bounds__(256, 2) void gemm_n512_kernel(
    const __hip_bfloat16* __restrict__ Q, const __hip_bfloat16* __restrict__ Wt3,
    const float* __restrict__ bias, float* __restrict__ out) {
  __shared__ __align__(16) char LDS[33792];   // max(A dbuf 20KB, epilogue 33KB)
  char* As0 = LDS;                            // 80 rows x 128B = 10240
  char* As1 = LDS + 10240;

  int tid  = threadIdx.x;
  int lane = tid & 63;
  int wave = tid >> 6;                // 0..3 (1M x 4N)
  int wc   = wave;                    // N-slice: cols wc*128 .. +127
  int m0 = blockIdx.x * 80;

  f32x4 acc[5][8] = {};

  const char* qb = reinterpret_cast<const char*>(Q);
  const char* w3 = reinterpret_cast<const char*>(Wt3);
  int sr8 = lane >> 3;                // row within 8-row group (0..7)
  int sc  = (lane & 7) * 16;          // 16B chunk within 128B row-block

  // A staging: 10 groups of 8 rows round-robined over 4 waves
  auto stageA = [&](char* Abuf, int ks) {
#pragma unroll
    for (int i = 0; i < 3; ++i) {
      int g = wave + i * 4;
      if (g < 10)
        gload_lds16(qb + (size_t)(m0 + g * 8 + sr8) * ROWB + (size_t)ks * 128 + sc,
                    Abuf + g * 1024);
    }
  };

  auto compute = [&](const char* Abuf, int ks) {
#pragma unroll
    for (int kk = 0; kk < 2; ++kk) {
      // B fragments straight from L2 (coalesced: lanes 0..15 = 256B run)
      const char* bp = w3 + ((size_t)(ks * 8 + kk * 4 + (lane >> 4)) * 512 +
                             (size_t)(wc * 128 + (lane & 15))) * 16;
      short8 bf[8];
#pragma unroll
      for (int nj = 0; nj < 8; ++nj)
        bf[nj] = *reinterpret_cast<const short8*>(bp + nj * 256);

      short8 af[5];
#pragma unroll
      for (int mi = 0; mi < 5; ++mi) {
        int r = mi * 16 + (lane & 15);
        int c7 = (kk * 4 + (lane >> 4)) ^ (r & 7);
        af[mi] = *reinterpret_cast<const short8*>(Abuf + r * 128 + c7 * 16);
      }
#pragma unroll
      for (int mi = 0; mi < 5; ++mi)
#pragma unroll
        for (int nj = 0; nj < 8; ++nj)
          acc[mi][nj] = __builtin_amdgcn_mfma_f32_16x16x32_bf16(
              af[mi], bf[nj], acc[mi][nj], 0, 0, 0);
    }
  };

  // ---- pipelined K-loop: 24 steps, stage(next) before compute(cur) ----
  stageA(As0, 0);
  __syncthreads();
  for (int ks = 0; ks < 22; ks += 2) {
    stageA(As1, ks + 1);
    compute(As0, ks);
    __syncthreads();
    stageA(As0, ks + 2);
    compute(As1, ks + 1);
    __syncthreads();
  }
  stageA(As1, 23);
  compute(As0, 22);
  __syncthreads();
  compute(As1, 23);
  __syncthreads();          // all compute done before epilogue reuses LDS

  // ---- epilogue: bias + LDS transpose-stage + plain float4 scatter ----
  float bs[8];
#pragma unroll
  for (int ni = 0; ni < 8; ++ni)
    bs[ni] = bias[wc * 128 + ni * 16 + (lane & 15)];

  char* eb = LDS + wave * 8448;       // 16 rows x 132 f32 per wave
  int halfsel = lane >> 5;            // 0/1
  int col4 = lane & 31;               // float4 col index (0..31)

#pragma unroll
  for (int mi = 0; mi < 5; ++mi) {
    // write 16 rows x 128 cols f32 with bias (stride 132: conflict-free)
#pragma unroll
    for (int ni = 0; ni < 8; ++ni)
#pragma unroll
      for (int j = 0; j < 4; ++j) {
        int row = (lane >> 4) * 4 + j;
        *reinterpret_cast<float*>(
            eb + ((row * 132 + ni * 16 + (lane & 15)) << 2)) =
            acc[mi][ni][j] + bs[ni];
      }
    // read back as float4 rows, scatter to joints (plain stores)
#pragma unroll
    for (int rr = 0; rr < 8; ++rr) {
      int row = rr * 2 + halfsel;
      u32x4 v4 = *reinterpret_cast<const u32x4*>(
          eb + ((row * 132 + col4 * 4) << 2));
      int R = m0 + mi * 16 + row;                 // part row = b*5+n
      unsigned bb = (unsigned)R / 5u;
      int n = R - (int)bb * 5;
      unsigned mask = (n == 0) ? 0x0000Eu :
                      (n == 1) ? 0x00070u :
                      (n == 2) ? 0x00781u :
                      (n == 3) ? 0x03800u : 0x1C000u;
      float* op = out + (size_t)bb * (NJ * DIM) + (wc * 128 + col4 * 4);
      while (mask) {
        int jn = __builtin_ctz(mask);
        mask &= mask - 1;
        *reinterpret_cast<u32x4*>(op + jn * DIM) = v4;
      }
    }
  }
}

extern "C" void kernel_launch(void* const* d_in, const int* in_sizes, int n_in,
                              void* d_out, int out_size, void* d_ws, size_t ws_size,
                              hipStream_t stream) {
  const float* x    = (const float*)d_in[0];   // [8192,17,512]
  const float* w    = (const float*)d_in[1];   // [3,1,512,512]
  const float* bias = (const float*)d_in[2];   // [1,1,512]
  float* out = (float*)d_out;                  // [8192,17,512]

  // ws layout: Wt3 [0,1.5MB) | Q [2MB, 122MB)
  __hip_bfloat16* Wt3 = (__hip_bfloat16*)d_ws;
  __hip_bfloat16* Q   = (__hip_bfloat16*)((char*)d_ws + (2u << 20));

  // host-side Cheb basis (K=2): T0=I, T1=L, T2=2L^2-I with L = I - rownorm(adj)
  Cheb cb;
  {
    double A[5][5] = {};
    const int e0[4] = {0, 1, 2, 2}, e1[4] = {2, 2, 3, 4};
    for (int t = 0; t < 4; ++t) { A[e0[t]][e1[t]] = 1.0; A[e1[t]][e0[t]] = 1.0; }
    for (int i = 0; i < 5; ++i) A[i][i] += 1.0;
    for (int i = 0; i < 5; ++i) {
      double rs = 0; for (int j = 0; j < 5; ++j) rs += A[i][j];
      for (int j = 0; j < 5; ++j) A[i][j] /= rs;
    }
    double L[5][5], T2[5][5];
    for (int i = 0; i < 5; ++i)
      for (int j = 0; j < 5; ++j) L[i][j] = (i == j ? 1.0 : 0.0) - A[i][j];
    for (int i = 0; i < 5; ++i)
      for (int j = 0; j < 5; ++j) {
        double s = 0; for (int m = 0; m < 5; ++m) s += L[i][m] * L[m][j];
        T2[i][j] = 2.0 * s - (i == j ? 1.0 : 0.0);
      }
    for (int i = 0; i < 5; ++i)
      for (int j = 0; j < 5; ++j) {
        cb.c[0][i][j] = (float)(i == j ? 1.0 : 0.0);
        cb.c[1][i][j] = (float)L[i][j];
        cb.c[2][i][j] = (float)T2[i][j];
      }
  }

  pool_cheb_kernel<<<(NB * 128) / 256, 256, 0, stream>>>(x, Q, cb);
  wt3_kernel<<<384, 256, 0, stream>>>(w, Wt3);
  gemm_n512_kernel<<<QROWS / 80, 256, 0, stream>>>(Q, Wt3, bias, out);
}